// Round 7
// baseline (297.365 us; speedup 1.0000x reference)
//
#include <hip/hip_runtime.h>

#define NBINS 15
#define NCLS  100
#define NSEG  (NBINS * NCLS)   // 1500
#define NGRP  64               // second-stage reduction groups
#define MAXBLK 2048            // 8 blocks/CU
#define BLK   256
#define SUMSCALE 2048.0f       // fixed-point scale for packed sum (20-bit field)
#define INV15 (1.0f / 15.0f)   // f32 edge arithmetic (round-2/5/6 proven vs np)

// Kernel 1: grid-stride float4 stream, TWO independent loads in flight per
// iteration (MLP). Bin index k computed directly (exact searchsorted-right
// semantics); ONE packed fire-and-forget ds_add_u32 per element:
// u32 = (1<<20) | round(p*2048)  ->  cnt in [31:20] exact, sum q2^-11.
// Partials flushed RAW (u32 pairs) - mid decodes - to halve partial traffic.
__global__ __launch_bounds__(BLK) void calib_accum(
    const float* __restrict__ probas,
    const int*   __restrict__ labels,
    unsigned int* __restrict__ partA,  // [nblk][2*NSEG] u32
    int total4)
{
    __shared__ unsigned int s_pk[NSEG];   // packed: cnt<<20 | sum*2048
    __shared__ unsigned int s_ac[NSEG];   // label-match counts
    const int t = threadIdx.x;
    for (int i = t; i < NSEG; i += BLK) { s_pk[i] = 0u; s_ac[i] = 0u; }
    __syncthreads();

    const float4* __restrict__ p4 = (const float4*)probas;
    const int stride = gridDim.x * BLK;

    for (int i = blockIdx.x * BLK + t; i < total4; i += 2 * stride) {
        // issue both float4 loads (and both label loads) before any use
        const int i1 = i + stride;
        float4 v0 = p4[i];
        float4 v1;
        if (i1 < total4) v1 = p4[i1];
        int row0 = i / 25;
        int lbl0 = labels[row0];
        int row1 = 0, lbl1 = 0;
        if (i1 < total4) { row1 = i1 / 25; lbl1 = labels[row1]; }

        #pragma unroll
        for (int h = 0; h < 2; ++h) {
            if (h == 1 && i1 >= total4) break;
            const int   ii  = (h == 0) ? i : i1;
            const int   row = (h == 0) ? row0 : row1;
            const int   lbl = (h == 0) ? lbl0 : lbl1;
            const float4 v  = (h == 0) ? v0 : v1;
            int col0 = (ii - row * 25) * 4;  // float4 never crosses a row
            float pv[4] = {v.x, v.y, v.z, v.w};
            #pragma unroll
            for (int j = 0; j < 4; ++j) {
                float p = pv[j];
                int c = col0 + j;
                // searchsorted(bins, p, 'right') - 1: largest k with bins[k] <= p
                int k = (int)(p * 15.0f);
                if (k < NBINS && (float)(k + 1) * INV15 <= p)      ++k;
                else if (k > 0 && (float)k * INV15 > p)            --k;
                float left = (float)k * INV15;
                if (p > 0.01f && k < NBINS && p > left) {
                    int seg = c * NBINS + k;
                    unsigned int pk = (1u << 20) | (unsigned int)(p * SUMSCALE + 0.5f);
                    atomicAdd(&s_pk[seg], pk);
                    if (lbl == c) atomicAdd(&s_ac[seg], 1u);
                }
            }
        }
    }
    __syncthreads();

    // flush raw packed partials (decode deferred to calib_mid)
    unsigned int* dst = partA + (size_t)blockIdx.x * (2 * NSEG);
    for (int s = t; s < NSEG; s += BLK) {
        dst[s]        = s_pk[s];
        dst[NSEG + s] = s_ac[s];
    }
}

// Kernel 2: NGRP-way parallel partial reduction over blocks (coalesced on s),
// decoding the packed partials.
__global__ __launch_bounds__(256) void calib_mid(
    const unsigned int* __restrict__ partA, int nblk, int chunk,
    float*              __restrict__ partB)   // [NGRP][3*NSEG]
{
    int t = blockIdx.x * 256 + threadIdx.x;
    if (t >= NGRP * NSEG) return;
    int g = t / NSEG;
    int s = t - g * NSEG;
    int b0 = g * chunk;
    int b1 = b0 + chunk; if (b1 > nblk) b1 = nblk;
    float cnt = 0.f, sum = 0.f, acc = 0.f;
    for (int b = b0; b < b1; ++b) {
        const unsigned int* src = partA + (size_t)b * (2 * NSEG);
        unsigned int pk = src[s];
        cnt += (float)(pk >> 20);
        sum += (float)(pk & 0xFFFFFu);
        acc += (float)src[NSEG + s];
    }
    float* dst = partB + (size_t)g * (3 * NSEG);
    dst[s]            = cnt;
    dst[NSEG + s]     = sum * (1.0f / SUMSCALE);
    dst[2 * NSEG + s] = acc;
}

// Kernel 3: final sum over NGRP groups, divide, NaN for empty bins.
__global__ __launch_bounds__(256) void calib_fin(
    const float* __restrict__ partB,
    float*       __restrict__ out)     // [confs(1500), accs(1500), n_samples(1500)]
{
    int s = blockIdx.x * 256 + threadIdx.x;
    if (s >= NSEG) return;
    float cnt = 0.f, sum = 0.f, acc = 0.f;
    #pragma unroll
    for (int g = 0; g < NGRP; ++g) {
        const float* src = partB + g * (3 * NSEG);
        cnt += src[s];
        sum += src[NSEG + s];
        acc += src[2 * NSEG + s];
    }
    float conf, accv;
    if (cnt > 0.f) { conf = sum / cnt; accv = acc / cnt; }
    else { conf = __int_as_float(0x7fc00000); accv = conf; }
    out[s]            = conf;
    out[NSEG + s]     = accv;
    out[2 * NSEG + s] = cnt;
}

extern "C" void kernel_launch(void* const* d_in, const int* in_sizes, int n_in,
                              void* d_out, int out_size, void* d_ws, size_t ws_size,
                              hipStream_t stream) {
    const float* probas = (const float*)d_in[0];
    const int*   labels = (const int*)d_in[1];
    float* out = (float*)d_out;

    int total  = in_sizes[0];      // N*C = 50,000,000 (divisible by 4; C=100)
    int total4 = total / 4;

    // workspace: partA [nblk][2*NSEG] u32, then partB [NGRP][3*NSEG] float
    size_t ws_words = ws_size / 4;
    long long avail = (long long)ws_words - (long long)NGRP * 3 * NSEG;
    int nblk = (int)(avail / (2 * NSEG));
    if (nblk > MAXBLK) nblk = MAXBLK;
    if (nblk < 1) nblk = 1;

    unsigned int* partA = (unsigned int*)d_ws;
    float*        partB = (float*)((unsigned int*)d_ws + (size_t)nblk * (2 * NSEG));

    calib_accum<<<nblk, BLK, 0, stream>>>(probas, labels, partA, total4);
    int chunk = (nblk + NGRP - 1) / NGRP;
    calib_mid<<<(NGRP * NSEG + 255) / 256, 256, 0, stream>>>(partA, nblk, chunk, partB);
    calib_fin<<<(NSEG + 255) / 256, 256, 0, stream>>>(partB, out);
}